// Round 7
// baseline (381.946 us; speedup 1.0000x reference)
//
#include <hip/hip_runtime.h>

#define HW 4096
#define NCH 256
#define DIM 128
#define NPROTO 512

typedef __attribute__((ext_vector_type(4))) float f32x4;
typedef __attribute__((ext_vector_type(8))) short s16x8;

__device__ __forceinline__ unsigned short f2bf(float f) {
  union { float f; unsigned u; } v; v.f = f;
  unsigned r = v.u + 0x7fffu + ((v.u >> 16) & 1u);
  return (unsigned short)(r >> 16);
}

// ---------------------------------------------------------------------------
// prep: P -> bf16 chunked Pr[ch][512][32] (+pn2); W -> bf16 row-major [128][256]
// ---------------------------------------------------------------------------
__global__ __launch_bounds__(256) void prep_kernel(const float* __restrict__ P,
                                                   const float* __restrict__ Wm,
                                                   unsigned short* __restrict__ Pr,
                                                   unsigned short* __restrict__ Wbf,
                                                   float* __restrict__ pn2) {
  const int tid = threadIdx.x;
  const int b = blockIdx.x;
  if (b < 8) {
    const int n  = b * 64 + (tid >> 2);
    const int qt = tid & 3;  // d-chunk 32*qt..
    const float* row = P + n * DIM + qt * 32;
    unsigned short* dst = Pr + ((size_t)qt * NPROTO + n) * 32;
    float ssq = 0.f;
#pragma unroll
    for (int u = 0; u < 8; ++u) {
      f32x4 v = *(const f32x4*)(row + 4 * u);
      ssq += v.x * v.x + v.y * v.y + v.z * v.z + v.w * v.w;
      dst[4 * u + 0] = f2bf(v.x);
      dst[4 * u + 1] = f2bf(v.y);
      dst[4 * u + 2] = f2bf(v.z);
      dst[4 * u + 3] = f2bf(v.w);
    }
    ssq += __shfl_xor(ssq, 1);
    ssq += __shfl_xor(ssq, 2);
    if (qt == 0) pn2[n] = ssq;
  } else {
    const int idx = ((b - 8) * 256 + tid) * 16;  // 8*256*16 = 32768 = 128*256
#pragma unroll
    for (int u = 0; u < 4; ++u) {
      f32x4 v = *(const f32x4*)(Wm + idx + 4 * u);
      unsigned short* d = Wbf + idx + 4 * u;
      d[0] = f2bf(v.x); d[1] = f2bf(v.y); d[2] = f2bf(v.z); d[3] = f2bf(v.w);
    }
  }
}

// ---------------------------------------------------------------------------
// fused (r6 structure, templated probe):
//   MODE 0 = FULL    (byte-identical schedule to round 6; correct output)
//   MODE 1 = NOSTORE (full compute chain, zero global stores; results kept
//                     live via asm keepalive — measures chain-minus-stores;
//                     launched at 4x grid so its dur row is visible)
// ---------------------------------------------------------------------------
template <int MODE>
__global__ __launch_bounds__(512, 4) void fused_kernel(
    const float* __restrict__ x, const unsigned short* __restrict__ Wbf,
    const float* __restrict__ bias, const unsigned short* __restrict__ Pr,
    const float* __restrict__ pn2, const float* __restrict__ gptr,
    float* __restrict__ out) {
  __shared__ __align__(16) char smem[18688];
  unsigned short* q_s = (unsigned short*)smem;  // [32][128] swizzled (8192)
  char* x_b = smem + 8192;                      // dbuf: 2 x (32 rows x 144B)
  float* red  = (float*)(smem + 17408);         // [8][32]
  float* rmx  = (float*)(smem + 18432);         // [32]
  float* rinv = (float*)(smem + 18560);         // [32]

  const int tid  = threadIdx.x;
  const int bid  = (MODE == 0) ? blockIdx.x : (blockIdx.x & 2047);
  const int p0   = bid * 32;
  const int nimg = p0 >> 12;
  const int hw0  = p0 & 4095;
  const int wave = tid >> 6, lane = tid & 63;
  const int l15 = lane & 15, l4 = lane >> 4;

  // ---- prologue: W fragments -> regs, then deep x prefetch ----
  const int dloc = 16 * wave + l15;  // this wave's d column for l15
  s16x8 wf[8];
  {
    const unsigned short* wrow = Wbf + (size_t)dloc * NCH + 8 * l4;
#pragma unroll
    for (int k = 0; k < 8; ++k) wf[k] = *(const s16x8*)(wrow + 32 * k);
  }

  const float* xb = x + (size_t)nimg * NCH * HW + hw0;
  const int f  = tid & 7;   // px quad: pixels 4f..4f+3
  const int cp = tid >> 3;  // channel pair 2cp,2cp+1 (stagers: tid<256)
  f32x4 xv[4][2];
  if (tid < 256) {
#pragma unroll
    for (int it = 0; it < 4; ++it) {
      xv[it][0] = *(const f32x4*)(xb + (size_t)(64 * it + 2 * cp + 0) * HW + 4 * f);
      xv[it][1] = *(const f32x4*)(xb + (size_t)(64 * it + 2 * cp + 1) * HW + 4 * f);
    }
  }
  const float bv = bias[dloc];

  // ---------------- phase 1: q = x W^T ----------------
  f32x4 acc1[2];
#pragma unroll
  for (int i = 0; i < 2; ++i)
#pragma unroll
    for (int r = 0; r < 4; ++r) acc1[i][r] = 0.f;

#pragma unroll
  for (int it = 0; it < 4; ++it) {
    char* xbuf = x_b + (it & 1) * 4608;
    if (tid < 256) {  // pack x(it): compiler waits exactly the xv[it] loads
#pragma unroll
      for (int s = 0; s < 4; ++s) {
        const int row = 4 * f + s;
        unsigned pk = (unsigned)f2bf(xv[it][0][s]) | ((unsigned)f2bf(xv[it][1][s]) << 16);
        *(unsigned*)(xbuf + row * 144 + ((4 * cp) ^ (((row >> 2) & 7) << 4))) = pk;
      }
    }
    asm volatile("s_waitcnt lgkmcnt(0)" ::: "memory");
    __builtin_amdgcn_s_barrier();
#pragma unroll
    for (int kc = 0; kc < 64; kc += 32) {
      const int ub = (kc >> 3) + l4;  // 16B unit 0..7
      s16x8 a[2];
#pragma unroll
      for (int i = 0; i < 2; ++i) {
        const int row = 16 * i + l15;
        a[i] = *(const s16x8*)(xbuf + row * 144 + 16 * (ub ^ ((row >> 2) & 7)));
      }
#pragma unroll
      for (int i = 0; i < 2; ++i)
        acc1[i] = __builtin_amdgcn_mfma_f32_16x16x32_bf16(a[i], wf[2 * it + (kc >> 5)],
                                                          acc1[i], 0, 0, 0);
    }
    // iter it+2's pack (same buf) fenced from this iter's readers by it+1's barrier
  }

  // ---------------- phase 1.5: q + bias -> q_s (swizzled bf16) ----------------
  {
    const int u = dloc >> 3, d7 = dloc & 7;
#pragma unroll
    for (int i = 0; i < 2; ++i) {
      const int pxb = 16 * i + 4 * l4;
#pragma unroll
      for (int r = 0; r < 4; ++r) {
        const int px = pxb + r;
        q_s[px * 128 + ((u ^ (px & 7)) << 3) + d7] = f2bf(acc1[i][r] + bv);
      }
    }
  }

  // ---------------- phase 2: attn, bq double-buffered from global ----------------
  f32x4 acc[2][4];
#pragma unroll
  for (int i = 0; i < 2; ++i)
#pragma unroll
    for (int j = 0; j < 4; ++j)
#pragma unroll
      for (int r = 0; r < 4; ++r) acc[i][j][r] = 0.f;

  s16x8 bqA[4], bqB[4];
#pragma unroll
  for (int j = 0; j < 4; ++j)
    bqA[j] = *(const s16x8*)(Pr + (size_t)(0 * NPROTO + 64 * wave + 16 * j + l15) * 32 + 8 * l4);
#pragma unroll
  for (int j = 0; j < 4; ++j)
    bqB[j] = *(const s16x8*)(Pr + (size_t)(1 * NPROTO + 64 * wave + 16 * j + l15) * 32 + 8 * l4);
  asm volatile("s_waitcnt lgkmcnt(0)" ::: "memory");
  __builtin_amdgcn_s_barrier();  // q_s visible; bq loads stay in flight

#define DO_CHUNK(CH, BQ)                                                        \
  {                                                                             \
    s16x8 afr[2];                                                               \
    _Pragma("unroll") for (int i = 0; i < 2; ++i) {                             \
      const int px = 16 * i + l15;                                              \
      afr[i] = *(const s16x8*)&q_s[px * 128 + (((4 * (CH) + l4) ^ (px & 7)) << 3)]; \
    }                                                                           \
    _Pragma("unroll") for (int j = 0; j < 4; ++j)                               \
      _Pragma("unroll") for (int i = 0; i < 2; ++i)                             \
        acc[i][j] = __builtin_amdgcn_mfma_f32_16x16x32_bf16(afr[i], BQ[j], acc[i][j], 0, 0, 0); \
  }

  DO_CHUNK(0, bqA);
#pragma unroll
  for (int j = 0; j < 4; ++j)  // refill A with chunk 2 (WAR on regs only)
    bqA[j] = *(const s16x8*)(Pr + (size_t)(2 * NPROTO + 64 * wave + 16 * j + l15) * 32 + 8 * l4);
  DO_CHUNK(1, bqB);
#pragma unroll
  for (int j = 0; j < 4; ++j)  // refill B with chunk 3
    bqB[j] = *(const s16x8*)(Pr + (size_t)(3 * NPROTO + 64 * wave + 16 * j + l15) * 32 + 8 * l4);
  DO_CHUNK(2, bqA);
  DO_CHUNK(3, bqB);
#undef DO_CHUNK

  // softmax over 512 protos (exp2 domain; qn2 row-constant cancels)
  const float g2  = fabsf(gptr[0]) * 1.44269504088896340736f;
  const float tg2 = 2.f * g2;
  float cj[4];
#pragma unroll
  for (int j = 0; j < 4; ++j) cj[j] = g2 * pn2[64 * wave + 16 * j + l15];

#pragma unroll
  for (int i = 0; i < 2; ++i)
#pragma unroll
    for (int r = 0; r < 4; ++r) {
      float m = -1e30f;
#pragma unroll
      for (int j = 0; j < 4; ++j) {
        float lv = fmaf(acc[i][j][r], tg2, -cj[j]);
        acc[i][j][r] = lv;
        m = fmaxf(m, lv);
      }
#pragma unroll
      for (int s = 1; s < 16; s <<= 1) m = fmaxf(m, __shfl_xor(m, s));
      if (l15 == 0) red[wave * 32 + 16 * i + 4 * l4 + r] = m;
    }
  __syncthreads();
  if (tid < 32) {
    float M = red[tid];
#pragma unroll
    for (int w = 1; w < 8; ++w) M = fmaxf(M, red[w * 32 + tid]);
    rmx[tid] = M;
  }
  __syncthreads();

#pragma unroll
  for (int i = 0; i < 2; ++i) {
    const f32x4 Mi = *(const f32x4*)&rmx[16 * i + 4 * l4];
#pragma unroll
    for (int r = 0; r < 4; ++r) {
      float s = 0.f;
#pragma unroll
      for (int j = 0; j < 4; ++j) {
        float e = exp2f(acc[i][j][r] - Mi[r]);
        acc[i][j][r] = e;
        s += e;
      }
#pragma unroll
      for (int t = 1; t < 16; t <<= 1) s += __shfl_xor(s, t);
      if (l15 == 0) red[wave * 32 + 16 * i + 4 * l4 + r] = s;
    }
  }
  __syncthreads();
  if (tid < 32) {
    float S = 0.f;
#pragma unroll
    for (int w = 0; w < 8; ++w) S += red[w * 32 + tid];
    rinv[tid] = 1.f / S;
  }
  __syncthreads();

  // epilogue: FULL stores f32x4; NOSTORE keeps values live, issues nothing
  float* ob = out + (size_t)nimg * NPROTO * HW + hw0;
#pragma unroll
  for (int i = 0; i < 2; ++i) {
    const f32x4 iv = *(const f32x4*)&rinv[16 * i + 4 * l4];
    const int px = 16 * i + 4 * l4;
#pragma unroll
    for (int j = 0; j < 4; ++j) {
      const int k = 64 * wave + 16 * j + l15;
      f32x4 o = acc[i][j] * iv;
      if constexpr (MODE == 0) {
        *(f32x4*)(ob + (size_t)k * HW + px) = o;
      } else {
        asm volatile("" ::"v"(o.x), "v"(o.y), "v"(o.z), "v"(o.w));
      }
    }
  }
}

extern "C" void kernel_launch(void* const* d_in, const int* in_sizes, int n_in,
                              void* d_out, int out_size, void* d_ws, size_t ws_size,
                              hipStream_t stream) {
  const float* x     = (const float*)d_in[0];
  const float* Wm    = (const float*)d_in[1];
  const float* bias  = (const float*)d_in[2];
  const float* prot  = (const float*)d_in[3];
  const float* gamma = (const float*)d_in[4];
  float* out = (float*)d_out;

  // workspace: Pr chunked bf16 (128 KiB) | pn2 (2 KiB) | W bf16 (64 KiB)
  unsigned short* Pr_w  = (unsigned short*)d_ws;
  float*          pn2_w = (float*)((char*)d_ws + 131072);
  unsigned short* W_ws  = (unsigned short*)((char*)d_ws + 131072 + 2048);

  prep_kernel<<<16, 256, 0, stream>>>(prot, Wm, Pr_w, W_ws, pn2_w);
  // diagnostic probe: full compute chain, zero stores, 4x grid (visible row)
  fused_kernel<1><<<8192, 512, 0, stream>>>(x, W_ws, bias, Pr_w, pn2_w, gamma, out);
  // the real kernel: unchanged r6 schedule, correct output, runs last
  fused_kernel<0><<<2048, 512, 0, stream>>>(x, W_ws, bias, Pr_w, pn2_w, gamma, out);
}

// Round 9
// 346.343 us; speedup vs baseline: 1.1028x; 1.1028x over previous
//
#include <hip/hip_runtime.h>

#define HW 4096
#define NCH 256
#define DIM 128
#define NPROTO 512

typedef __attribute__((ext_vector_type(4))) float f32x4;
typedef __attribute__((ext_vector_type(8))) short s16x8;

__device__ __forceinline__ unsigned short f2bf(float f) {
  union { float f; unsigned u; } v; v.f = f;
  unsigned r = v.u + 0x7fffu + ((v.u >> 16) & 1u);
  return (unsigned short)(r >> 16);
}

// ---------------------------------------------------------------------------
// prep: P -> bf16 chunked Pr[ch][512][32] (+pn2); W -> bf16 row-major [128][256]
// ---------------------------------------------------------------------------
__global__ __launch_bounds__(256) void prep_kernel(const float* __restrict__ P,
                                                   const float* __restrict__ Wm,
                                                   unsigned short* __restrict__ Pr,
                                                   unsigned short* __restrict__ Wbf,
                                                   float* __restrict__ pn2) {
  const int tid = threadIdx.x;
  const int b = blockIdx.x;
  if (b < 8) {
    const int n  = b * 64 + (tid >> 2);
    const int qt = tid & 3;  // d-chunk 32*qt..
    const float* row = P + n * DIM + qt * 32;
    unsigned short* dst = Pr + ((size_t)qt * NPROTO + n) * 32;
    float ssq = 0.f;
#pragma unroll
    for (int u = 0; u < 8; ++u) {
      f32x4 v = *(const f32x4*)(row + 4 * u);
      ssq += v.x * v.x + v.y * v.y + v.z * v.z + v.w * v.w;
      dst[4 * u + 0] = f2bf(v.x);
      dst[4 * u + 1] = f2bf(v.y);
      dst[4 * u + 2] = f2bf(v.z);
      dst[4 * u + 3] = f2bf(v.w);
    }
    ssq += __shfl_xor(ssq, 1);
    ssq += __shfl_xor(ssq, 2);
    if (qt == 0) pn2[n] = ssq;
  } else {
    const int idx = ((b - 8) * 256 + tid) * 16;  // 8*256*16 = 32768 = 128*256
#pragma unroll
    for (int u = 0; u < 4; ++u) {
      f32x4 v = *(const f32x4*)(Wm + idx + 4 * u);
      unsigned short* d = Wbf + idx + 4 * u;
      d[0] = f2bf(v.x); d[1] = f2bf(v.y); d[2] = f2bf(v.z); d[3] = f2bf(v.w);
    }
  }
}

// ---------------------------------------------------------------------------
// fused v4 (persistent): 512 blocks x 512 thr; block owns 128 px = 4 tiles
// of 32 px, looped. Why (from r7 probe): per-CU time = SUM of per-block
// latencies (zero inter-block overlap; stores drain before slot frees;
// VGPR=48 proved r6's prefetch was compiler-sunk). So:
//   - stores of tile t drain under tile t+1's compute (no wait at issue)
//   - x prefetch rolls 2 K-steps ahead CONTINUOUSLY across tiles (in flight
//     through softmax), pinned with sched_barrier(0) so it can't be sunk
//   - W fragments -> regs ONCE per block (4x fewer W loads, L2-hot)
//   - all 4 tiles share nimg/base (128 px never crosses an image boundary)
// Per-tile schedule byte-level identical to r6 (proven correct): pack ->
// lgkm+barrier -> ds_read+MFMA per K-iter; swizzled q_s; bq dbuf; exp2
// softmax; direct f32x4 stores.
// ---------------------------------------------------------------------------
__global__ __launch_bounds__(512, 4) void fused_kernel(
    const float* __restrict__ x, const unsigned short* __restrict__ Wbf,
    const float* __restrict__ bias, const unsigned short* __restrict__ Pr,
    const float* __restrict__ pn2, const float* __restrict__ gptr,
    float* __restrict__ out) {
  __shared__ __align__(16) char smem[18688];
  unsigned short* q_s = (unsigned short*)smem;  // [32][128] swizzled (8192)
  char* x_b = smem + 8192;                      // dbuf: 2 x (32 rows x 144B)
  float* red  = (float*)(smem + 17408);         // [8][32]
  float* rmx  = (float*)(smem + 18432);         // [32]
  float* rinv = (float*)(smem + 18560);         // [32]

  const int tid  = threadIdx.x;
  const int bid  = blockIdx.x;
  const int pB   = bid * 128;        // 128 consecutive px, same image
  const int nimg = pB >> 12;
  const int hw0  = pB & 4095;
  const int wave = tid >> 6, lane = tid & 63;
  const int l15 = lane & 15, l4 = lane >> 4;

  // ---- per-block prologue (issued once, pinned) ----
  const int dloc = 16 * wave + l15;  // this wave's d column for l15
  s16x8 wf[8];
  {
    const unsigned short* wrow = Wbf + (size_t)dloc * NCH + 8 * l4;
#pragma unroll
    for (int k = 0; k < 8; ++k) wf[k] = *(const s16x8*)(wrow + 32 * k);
  }
  const float* xbB = x + (size_t)nimg * NCH * HW + hw0;
  float* obB = out + (size_t)nimg * NPROTO * HW + hw0;
  const int f  = tid & 7;   // px quad within tile: pixels 4f..4f+3
  const int cp = tid >> 3;  // channel pair 2cp,2cp+1 (stagers: tid<256)

  f32x4 xv[2][2];  // rolling 2-deep: slot g&1 holds K-step g's x
  if (tid < 256) {
#pragma unroll
    for (int g = 0; g < 2; ++g) {  // g: global K-iter index (tile g>>2, c0 (g&3)*64)
      xv[g][0] = *(const f32x4*)(xbB + (size_t)(64 * g + 2 * cp + 0) * HW + 4 * f);
      xv[g][1] = *(const f32x4*)(xbB + (size_t)(64 * g + 2 * cp + 1) * HW + 4 * f);
    }
  }
  const float bv = bias[dloc];
  const float g2  = fabsf(gptr[0]) * 1.44269504088896340736f;
  const float tg2 = 2.f * g2;
  float cj[4];
#pragma unroll
  for (int j = 0; j < 4; ++j) cj[j] = g2 * pn2[64 * wave + 16 * j + l15];
  __builtin_amdgcn_sched_barrier(0);  // pin all prologue load issues here

#pragma unroll
  for (int t = 0; t < 4; ++t) {
    // ---------------- phase 1: q = x W^T (K-iters g = 4t..4t+3) ----------------
    f32x4 acc1[2];
#pragma unroll
    for (int i = 0; i < 2; ++i)
#pragma unroll
      for (int r = 0; r < 4; ++r) acc1[i][r] = 0.f;

#pragma unroll
    for (int it = 0; it < 4; ++it) {
      const int g = 4 * t + it;
      char* xbuf = x_b + (g & 1) * 4608;
      if (tid < 256) {
        // pack x(g): reg-dep wait drains the load issued at g-2
#pragma unroll
        for (int s = 0; s < 4; ++s) {
          const int row = 4 * f + s;
          unsigned pk = (unsigned)f2bf(xv[g & 1][0][s]) |
                        ((unsigned)f2bf(xv[g & 1][1][s]) << 16);
          *(unsigned*)(xbuf + row * 144 + ((4 * cp) ^ (((row >> 2) & 7) << 4))) = pk;
        }
        if (g + 2 < 16) {  // issue x(g+2) into the freed slot; 2-deep in flight
          const int tt = (g + 2) >> 2, cc = ((g + 2) & 3) * 64;
          xv[g & 1][0] = *(const f32x4*)(xbB + (size_t)(cc + 2 * cp + 0) * HW + 32 * tt + 4 * f);
          xv[g & 1][1] = *(const f32x4*)(xbB + (size_t)(cc + 2 * cp + 1) * HW + 32 * tt + 4 * f);
        }
      }
      __builtin_amdgcn_sched_barrier(0);  // pin prefetch issue before the barrier
      asm volatile("s_waitcnt lgkmcnt(0)" ::: "memory");
      __builtin_amdgcn_s_barrier();
#pragma unroll
      for (int kc = 0; kc < 64; kc += 32) {
        const int ub = (kc >> 3) + l4;  // 16B unit 0..7
        s16x8 a[2];
#pragma unroll
        for (int i = 0; i < 2; ++i) {
          const int row = 16 * i + l15;
          a[i] = *(const s16x8*)(xbuf + row * 144 + 16 * (ub ^ ((row >> 2) & 7)));
        }
#pragma unroll
        for (int i = 0; i < 2; ++i)
          acc1[i] = __builtin_amdgcn_mfma_f32_16x16x32_bf16(a[i], wf[2 * it + (kc >> 5)],
                                                            acc1[i], 0, 0, 0);
      }
      // pack(g+2) of the same buffer is fenced from these readers by the
      // top barrier of iter g+1 (each wave: mfma(g) precedes barrier(g+1))
    }

    // ---------------- phase 1.5: q + bias -> q_s (swizzled bf16) ----------------
    {
      const int u = dloc >> 3, d7 = dloc & 7;
#pragma unroll
      for (int i = 0; i < 2; ++i) {
        const int pxb = 16 * i + 4 * l4;
#pragma unroll
        for (int r = 0; r < 4; ++r) {
          const int px = pxb + r;
          q_s[px * 128 + ((u ^ (px & 7)) << 3) + d7] = f2bf(acc1[i][r] + bv);
        }
      }
    }

    // ---------------- phase 2: attn, bq double-buffered from L2 ----------------
    f32x4 acc[2][4];
#pragma unroll
    for (int i = 0; i < 2; ++i)
#pragma unroll
      for (int j = 0; j < 4; ++j)
#pragma unroll
        for (int r = 0; r < 4; ++r) acc[i][j][r] = 0.f;

    s16x8 bqA[4], bqB[4];
#pragma unroll
    for (int j = 0; j < 4; ++j)
      bqA[j] = *(const s16x8*)(Pr + (size_t)(0 * NPROTO + 64 * wave + 16 * j + l15) * 32 + 8 * l4);
#pragma unroll
    for (int j = 0; j < 4; ++j)
      bqB[j] = *(const s16x8*)(Pr + (size_t)(1 * NPROTO + 64 * wave + 16 * j + l15) * 32 + 8 * l4);
    __builtin_amdgcn_sched_barrier(0);
    asm volatile("s_waitcnt lgkmcnt(0)" ::: "memory");
    __builtin_amdgcn_s_barrier();  // q_s visible; bq loads stay in flight

#define DO_CHUNK(CH, BQ)                                                        \
    {                                                                           \
      s16x8 afr[2];                                                             \
      _Pragma("unroll") for (int i = 0; i < 2; ++i) {                           \
        const int px = 16 * i + l15;                                            \
        afr[i] = *(const s16x8*)&q_s[px * 128 + (((4 * (CH) + l4) ^ (px & 7)) << 3)]; \
      }                                                                         \
      _Pragma("unroll") for (int j = 0; j < 4; ++j)                             \
        _Pragma("unroll") for (int i = 0; i < 2; ++i)                           \
          acc[i][j] = __builtin_amdgcn_mfma_f32_16x16x32_bf16(afr[i], BQ[j], acc[i][j], 0, 0, 0); \
    }

    DO_CHUNK(0, bqA);
#pragma unroll
    for (int j = 0; j < 4; ++j)  // refill A with chunk 2 (WAR on regs only)
      bqA[j] = *(const s16x8*)(Pr + (size_t)(2 * NPROTO + 64 * wave + 16 * j + l15) * 32 + 8 * l4);
    __builtin_amdgcn_sched_barrier(0);  // pin refill issue under chunk-1 MFMAs
    DO_CHUNK(1, bqB);
#pragma unroll
    for (int j = 0; j < 4; ++j)  // refill B with chunk 3
      bqB[j] = *(const s16x8*)(Pr + (size_t)(3 * NPROTO + 64 * wave + 16 * j + l15) * 32 + 8 * l4);
    __builtin_amdgcn_sched_barrier(0);
    DO_CHUNK(2, bqA);
    DO_CHUNK(3, bqB);
#undef DO_CHUNK

    // ---------------- softmax over 512 protos (exp2 domain) ----------------
#pragma unroll
    for (int i = 0; i < 2; ++i)
#pragma unroll
      for (int r = 0; r < 4; ++r) {
        float m = -1e30f;
#pragma unroll
        for (int j = 0; j < 4; ++j) {
          float lv = fmaf(acc[i][j][r], tg2, -cj[j]);
          acc[i][j][r] = lv;
          m = fmaxf(m, lv);
        }
#pragma unroll
        for (int s = 1; s < 16; s <<= 1) m = fmaxf(m, __shfl_xor(m, s));
        if (l15 == 0) red[wave * 32 + 16 * i + 4 * l4 + r] = m;
      }
    __syncthreads();
    if (tid < 32) {
      float M = red[tid];
#pragma unroll
      for (int w = 1; w < 8; ++w) M = fmaxf(M, red[w * 32 + tid]);
      rmx[tid] = M;
    }
    __syncthreads();

#pragma unroll
    for (int i = 0; i < 2; ++i) {
      const f32x4 Mi = *(const f32x4*)&rmx[16 * i + 4 * l4];
#pragma unroll
      for (int r = 0; r < 4; ++r) {
        float s = 0.f;
#pragma unroll
        for (int j = 0; j < 4; ++j) {
          float e = exp2f(acc[i][j][r] - Mi[r]);
          acc[i][j][r] = e;
          s += e;
        }
#pragma unroll
        for (int tt = 1; tt < 16; tt <<= 1) s += __shfl_xor(s, tt);
        if (l15 == 0) red[wave * 32 + 16 * i + 4 * l4 + r] = s;
      }
    }
    __syncthreads();
    if (tid < 32) {
      float S = 0.f;
#pragma unroll
      for (int w = 0; w < 8; ++w) S += red[w * 32 + tid];
      rinv[tid] = 1.f / S;
    }
    __syncthreads();

    // ---------------- epilogue: issue stores, do NOT wait ----------------
    // store data lives in its own regs; the drain overlaps tile t+1's
    // phase 1 (the next vmcnt pressure point is ~a full tile away)
#pragma unroll
    for (int i = 0; i < 2; ++i) {
      const f32x4 iv = *(const f32x4*)&rinv[16 * i + 4 * l4];
      const int px = 16 * i + 4 * l4 + 32 * t;
#pragma unroll
      for (int j = 0; j < 4; ++j) {
        const int k = 64 * wave + 16 * j + l15;
        f32x4 o = acc[i][j] * iv;
        *(f32x4*)(obB + (size_t)k * HW + px) = o;
      }
    }
  }
}

extern "C" void kernel_launch(void* const* d_in, const int* in_sizes, int n_in,
                              void* d_out, int out_size, void* d_ws, size_t ws_size,
                              hipStream_t stream) {
  const float* x     = (const float*)d_in[0];
  const float* Wm    = (const float*)d_in[1];
  const float* bias  = (const float*)d_in[2];
  const float* prot  = (const float*)d_in[3];
  const float* gamma = (const float*)d_in[4];
  float* out = (float*)d_out;

  // workspace: Pr chunked bf16 (128 KiB) | pn2 (2 KiB) | W bf16 (64 KiB)
  unsigned short* Pr_w  = (unsigned short*)d_ws;
  float*          pn2_w = (float*)((char*)d_ws + 131072);
  unsigned short* W_ws  = (unsigned short*)((char*)d_ws + 131072 + 2048);

  prep_kernel<<<16, 256, 0, stream>>>(prot, Wm, Pr_w, W_ws, pn2_w);
  fused_kernel<<<512, 512, 0, stream>>>(x, W_ws, bias, Pr_w, pn2_w, gamma, out);
}

// Round 10
// 219.058 us; speedup vs baseline: 1.7436x; 1.5811x over previous
//
#include <hip/hip_runtime.h>

#define HW 4096
#define NCH 256
#define DIM 128
#define NPROTO 512

typedef __attribute__((ext_vector_type(4))) float f32x4;
typedef __attribute__((ext_vector_type(8))) short s16x8;

__device__ __forceinline__ unsigned short f2bf(float f) {
  union { float f; unsigned u; } v; v.f = f;
  unsigned r = v.u + 0x7fffu + ((v.u >> 16) & 1u);
  return (unsigned short)(r >> 16);
}

// ---------------------------------------------------------------------------
// prep: P -> bf16 chunked Pr[ch][512][32] (+pn2); W -> bf16 row-major [128][256]
// ---------------------------------------------------------------------------
__global__ __launch_bounds__(256) void prep_kernel(const float* __restrict__ P,
                                                   const float* __restrict__ Wm,
                                                   unsigned short* __restrict__ Pr,
                                                   unsigned short* __restrict__ Wbf,
                                                   float* __restrict__ pn2) {
  const int tid = threadIdx.x;
  const int b = blockIdx.x;
  if (b < 8) {
    const int n  = b * 64 + (tid >> 2);
    const int qt = tid & 3;  // d-chunk 32*qt..
    const float* row = P + n * DIM + qt * 32;
    unsigned short* dst = Pr + ((size_t)qt * NPROTO + n) * 32;
    float ssq = 0.f;
#pragma unroll
    for (int u = 0; u < 8; ++u) {
      f32x4 v = *(const f32x4*)(row + 4 * u);
      ssq += v.x * v.x + v.y * v.y + v.z * v.z + v.w * v.w;
      dst[4 * u + 0] = f2bf(v.x);
      dst[4 * u + 1] = f2bf(v.y);
      dst[4 * u + 2] = f2bf(v.z);
      dst[4 * u + 3] = f2bf(v.w);
    }
    ssq += __shfl_xor(ssq, 1);
    ssq += __shfl_xor(ssq, 2);
    if (qt == 0) pn2[n] = ssq;
  } else {
    const int idx = ((b - 8) * 256 + tid) * 16;  // 8*256*16 = 32768 = 128*256
#pragma unroll
    for (int u = 0; u < 4; ++u) {
      f32x4 v = *(const f32x4*)(Wm + idx + 4 * u);
      unsigned short* d = Wbf + idx + 4 * u;
      d[0] = f2bf(v.x); d[1] = f2bf(v.y); d[2] = f2bf(v.z); d[3] = f2bf(v.w);
    }
  }
}

// ---------------------------------------------------------------------------
// fused v5: r6 structure VERBATIM (2048 blocks x 512 thr, 32 px/block,
// exit-at-end stores -- the config with WRITE_SIZE == output exactly),
// with ONE change: phase-1 x prefetch is ROLLING 2 K-steps ahead and
// PINNED with sched_barrier(0) so the compiler cannot sink it to the use
// point (r6's VGPR=48 proved its xv[4] prefetch was sunk; r7's probe
// showed the per-block serial chain ~6.1us ~= 4 exposed x-load latencies).
// Everything else (W frags in regs, swizzled q_s, bq dbuf phase 2, exp2
// softmax, direct f32x4 stores) is byte-identical to r6.
// ---------------------------------------------------------------------------
__global__ __launch_bounds__(512, 4) void fused_kernel(
    const float* __restrict__ x, const unsigned short* __restrict__ Wbf,
    const float* __restrict__ bias, const unsigned short* __restrict__ Pr,
    const float* __restrict__ pn2, const float* __restrict__ gptr,
    float* __restrict__ out) {
  __shared__ __align__(16) char smem[18688];
  unsigned short* q_s = (unsigned short*)smem;  // [32][128] swizzled (8192)
  char* x_b = smem + 8192;                      // dbuf: 2 x (32 rows x 144B)
  float* red  = (float*)(smem + 17408);         // [8][32]
  float* rmx  = (float*)(smem + 18432);         // [32]
  float* rinv = (float*)(smem + 18560);         // [32]

  const int tid  = threadIdx.x;
  const int p0   = blockIdx.x * 32;
  const int nimg = p0 >> 12;
  const int hw0  = p0 & 4095;
  const int wave = tid >> 6, lane = tid & 63;
  const int l15 = lane & 15, l4 = lane >> 4;

  // ---- prologue: W fragments -> regs + first 2 x K-steps, pinned ----
  const int dloc = 16 * wave + l15;  // this wave's d column for l15
  s16x8 wf[8];
  {
    const unsigned short* wrow = Wbf + (size_t)dloc * NCH + 8 * l4;
#pragma unroll
    for (int k = 0; k < 8; ++k) wf[k] = *(const s16x8*)(wrow + 32 * k);
  }

  const float* xb = x + (size_t)nimg * NCH * HW + hw0;
  const int f  = tid & 7;   // px quad: pixels 4f..4f+3
  const int cp = tid >> 3;  // channel pair 2cp,2cp+1 (stagers: tid<256)
  f32x4 xv[2][2];           // rolling 2-deep: slot g&1 holds K-step g's x
  if (tid < 256) {
#pragma unroll
    for (int g = 0; g < 2; ++g) {
      xv[g][0] = *(const f32x4*)(xb + (size_t)(64 * g + 2 * cp + 0) * HW + 4 * f);
      xv[g][1] = *(const f32x4*)(xb + (size_t)(64 * g + 2 * cp + 1) * HW + 4 * f);
    }
  }
  const float bv = bias[dloc];
  __builtin_amdgcn_sched_barrier(0);  // pin prologue load issues here

  // ---------------- phase 1: q = x W^T ----------------
  f32x4 acc1[2];
#pragma unroll
  for (int i = 0; i < 2; ++i)
#pragma unroll
    for (int r = 0; r < 4; ++r) acc1[i][r] = 0.f;

#pragma unroll
  for (int it = 0; it < 4; ++it) {
    char* xbuf = x_b + (it & 1) * 4608;
    if (tid < 256) {
      // pack x(it): reg-dep wait drains the load issued at it-2 (deep)
#pragma unroll
      for (int s = 0; s < 4; ++s) {
        const int row = 4 * f + s;
        unsigned pk = (unsigned)f2bf(xv[it & 1][0][s]) |
                      ((unsigned)f2bf(xv[it & 1][1][s]) << 16);
        *(unsigned*)(xbuf + row * 144 + ((4 * cp) ^ (((row >> 2) & 7) << 4))) = pk;
      }
      if (it + 2 < 4) {  // refill freed slot with K-step it+2; stays in flight
        const int cc = 64 * (it + 2);
        xv[it & 1][0] = *(const f32x4*)(xb + (size_t)(cc + 2 * cp + 0) * HW + 4 * f);
        xv[it & 1][1] = *(const f32x4*)(xb + (size_t)(cc + 2 * cp + 1) * HW + 4 * f);
      }
    }
    __builtin_amdgcn_sched_barrier(0);  // pin refill issue before the barrier
    asm volatile("s_waitcnt lgkmcnt(0)" ::: "memory");
    __builtin_amdgcn_s_barrier();
#pragma unroll
    for (int kc = 0; kc < 64; kc += 32) {
      const int ub = (kc >> 3) + l4;  // 16B unit 0..7
      s16x8 a[2];
#pragma unroll
      for (int i = 0; i < 2; ++i) {
        const int row = 16 * i + l15;
        a[i] = *(const s16x8*)(xbuf + row * 144 + 16 * (ub ^ ((row >> 2) & 7)));
      }
#pragma unroll
      for (int i = 0; i < 2; ++i)
        acc1[i] = __builtin_amdgcn_mfma_f32_16x16x32_bf16(a[i], wf[2 * it + (kc >> 5)],
                                                          acc1[i], 0, 0, 0);
    }
    // pack(it+2) of this buffer is fenced from these readers by iter it+1's
    // barrier (each wave's lgkmcnt(0) before that barrier drains its ds_reads)
  }

  // ---------------- phase 1.5: q + bias -> q_s (swizzled bf16) ----------------
  {
    const int u = dloc >> 3, d7 = dloc & 7;
#pragma unroll
    for (int i = 0; i < 2; ++i) {
      const int pxb = 16 * i + 4 * l4;
#pragma unroll
      for (int r = 0; r < 4; ++r) {
        const int px = pxb + r;
        q_s[px * 128 + ((u ^ (px & 7)) << 3) + d7] = f2bf(acc1[i][r] + bv);
      }
    }
  }

  // ---------------- phase 2: attn, bq double-buffered from global ----------------
  f32x4 acc[2][4];
#pragma unroll
  for (int i = 0; i < 2; ++i)
#pragma unroll
    for (int j = 0; j < 4; ++j)
#pragma unroll
      for (int r = 0; r < 4; ++r) acc[i][j][r] = 0.f;

  s16x8 bqA[4], bqB[4];
#pragma unroll
  for (int j = 0; j < 4; ++j)
    bqA[j] = *(const s16x8*)(Pr + (size_t)(0 * NPROTO + 64 * wave + 16 * j + l15) * 32 + 8 * l4);
#pragma unroll
  for (int j = 0; j < 4; ++j)
    bqB[j] = *(const s16x8*)(Pr + (size_t)(1 * NPROTO + 64 * wave + 16 * j + l15) * 32 + 8 * l4);
  asm volatile("s_waitcnt lgkmcnt(0)" ::: "memory");
  __builtin_amdgcn_s_barrier();  // q_s visible; bq loads stay in flight

#define DO_CHUNK(CH, BQ)                                                        \
  {                                                                             \
    s16x8 afr[2];                                                               \
    _Pragma("unroll") for (int i = 0; i < 2; ++i) {                             \
      const int px = 16 * i + l15;                                              \
      afr[i] = *(const s16x8*)&q_s[px * 128 + (((4 * (CH) + l4) ^ (px & 7)) << 3)]; \
    }                                                                           \
    _Pragma("unroll") for (int j = 0; j < 4; ++j)                               \
      _Pragma("unroll") for (int i = 0; i < 2; ++i)                             \
        acc[i][j] = __builtin_amdgcn_mfma_f32_16x16x32_bf16(afr[i], BQ[j], acc[i][j], 0, 0, 0); \
  }

  DO_CHUNK(0, bqA);
#pragma unroll
  for (int j = 0; j < 4; ++j)  // refill A with chunk 2 (WAR on regs only)
    bqA[j] = *(const s16x8*)(Pr + (size_t)(2 * NPROTO + 64 * wave + 16 * j + l15) * 32 + 8 * l4);
  DO_CHUNK(1, bqB);
#pragma unroll
  for (int j = 0; j < 4; ++j)  // refill B with chunk 3
    bqB[j] = *(const s16x8*)(Pr + (size_t)(3 * NPROTO + 64 * wave + 16 * j + l15) * 32 + 8 * l4);
  DO_CHUNK(2, bqA);
  DO_CHUNK(3, bqB);
#undef DO_CHUNK

  // softmax over 512 protos (exp2 domain; qn2 row-constant cancels)
  const float g2  = fabsf(gptr[0]) * 1.44269504088896340736f;
  const float tg2 = 2.f * g2;
  float cj[4];
#pragma unroll
  for (int j = 0; j < 4; ++j) cj[j] = g2 * pn2[64 * wave + 16 * j + l15];

#pragma unroll
  for (int i = 0; i < 2; ++i)
#pragma unroll
    for (int r = 0; r < 4; ++r) {
      float m = -1e30f;
#pragma unroll
      for (int j = 0; j < 4; ++j) {
        float lv = fmaf(acc[i][j][r], tg2, -cj[j]);
        acc[i][j][r] = lv;
        m = fmaxf(m, lv);
      }
#pragma unroll
      for (int s = 1; s < 16; s <<= 1) m = fmaxf(m, __shfl_xor(m, s));
      if (l15 == 0) red[wave * 32 + 16 * i + 4 * l4 + r] = m;
    }
  __syncthreads();
  if (tid < 32) {
    float M = red[tid];
#pragma unroll
    for (int w = 1; w < 8; ++w) M = fmaxf(M, red[w * 32 + tid]);
    rmx[tid] = M;
  }
  __syncthreads();

#pragma unroll
  for (int i = 0; i < 2; ++i) {
    const f32x4 Mi = *(const f32x4*)&rmx[16 * i + 4 * l4];
#pragma unroll
    for (int r = 0; r < 4; ++r) {
      float s = 0.f;
#pragma unroll
      for (int j = 0; j < 4; ++j) {
        float e = exp2f(acc[i][j][r] - Mi[r]);
        acc[i][j][r] = e;
        s += e;
      }
#pragma unroll
      for (int t = 1; t < 16; t <<= 1) s += __shfl_xor(s, t);
      if (l15 == 0) red[wave * 32 + 16 * i + 4 * l4 + r] = s;
    }
  }
  __syncthreads();
  if (tid < 32) {
    float S = 0.f;
#pragma unroll
    for (int w = 0; w < 8; ++w) S += red[w * 32 + tid];
    rinv[tid] = 1.f / S;
  }
  __syncthreads();

  // direct stores: f32x4 over r = 4 consecutive px (exit-at-end, merges to
  // full lines -- the r4/r6-verified pattern with WRITE_SIZE == output)
  float* ob = out + (size_t)nimg * NPROTO * HW + hw0;
#pragma unroll
  for (int i = 0; i < 2; ++i) {
    const f32x4 iv = *(const f32x4*)&rinv[16 * i + 4 * l4];
    const int px = 16 * i + 4 * l4;
#pragma unroll
    for (int j = 0; j < 4; ++j) {
      const int k = 64 * wave + 16 * j + l15;
      f32x4 o = acc[i][j] * iv;
      *(f32x4*)(ob + (size_t)k * HW + px) = o;
    }
  }
}

extern "C" void kernel_launch(void* const* d_in, const int* in_sizes, int n_in,
                              void* d_out, int out_size, void* d_ws, size_t ws_size,
                              hipStream_t stream) {
  const float* x     = (const float*)d_in[0];
  const float* Wm    = (const float*)d_in[1];
  const float* bias  = (const float*)d_in[2];
  const float* prot  = (const float*)d_in[3];
  const float* gamma = (const float*)d_in[4];
  float* out = (float*)d_out;

  // workspace: Pr chunked bf16 (128 KiB) | pn2 (2 KiB) | W bf16 (64 KiB)
  unsigned short* Pr_w  = (unsigned short*)d_ws;
  float*          pn2_w = (float*)((char*)d_ws + 131072);
  unsigned short* W_ws  = (unsigned short*)((char*)d_ws + 131072 + 2048);

  prep_kernel<<<16, 256, 0, stream>>>(prot, Wm, Pr_w, W_ws, pn2_w);
  fused_kernel<<<2048, 512, 0, stream>>>(x, W_ws, bias, Pr_w, pn2_w, gamma, out);
}